// Round 2
// baseline (876.631 us; speedup 1.0000x reference)
//
#include <hip/hip_runtime.h>
#include <cstdint>

#define NQ 196
#define DIMX 384
#define QKVD 2304
#define VAD 1536
#define NHD 12
#define MTOT 25088  // 128*196

typedef unsigned int u32;
typedef unsigned short u16;
typedef __bf16 bf16_t;
typedef bf16_t bf16x8 __attribute__((ext_vector_type(8)));
typedef float f32x4 __attribute__((ext_vector_type(4)));

__device__ inline u16 f2b(float f) {
  u32 u = __float_as_uint(f);
  u32 r = (u + 0x7fffu + ((u >> 16) & 1u)) >> 16;
  return (u16)r;
}
__device__ inline float b2f(u16 u) { return __uint_as_float(((u32)u) << 16); }
__device__ inline int iabs(int v) { return v < 0 ? -v : v; }

__device__ inline void gld_lds16(const void* g, void* l) {
  __builtin_amdgcn_global_load_lds((__attribute__((address_space(1))) void*)g,
                                   (__attribute__((address_space(3))) void*)l,
                                   16, 0, 0);
}

// ---------------- conversion / BN-table helpers ----------------

__global__ void cvt_kernel(const float* __restrict__ in, u16* __restrict__ out, int n4) {
  int i = blockIdx.x * 256 + threadIdx.x;
  if (i >= n4) return;
  float4 v = ((const float4*)in)[i];
  ushort4 o;
  o.x = f2b(v.x); o.y = f2b(v.y); o.z = f2b(v.z); o.w = f2b(v.w);
  ((ushort4*)out)[i] = o;
}

__global__ void bn_tab(const float* __restrict__ g, const float* __restrict__ be,
                       const float* __restrict__ mn, const float* __restrict__ vr,
                       float* __restrict__ inv, float* __restrict__ off, int n) {
  int i = blockIdx.x * 256 + threadIdx.x;
  if (i >= n) return;
  float iv = g[i] * rsqrtf(vr[i] + 1e-5f);
  inv[i] = iv;
  off[i] = be[i] - mn[i] * iv;
}

// ---------------- bf16 MFMA GEMM, C = A * B^T (both K-contiguous) ----------------
// MODE 0: QKV epilogue (BN fold + scatter to Q/K/V bf16)
// MODE 1: proj epilogue (BN fold, fp32 out)

template <int MODE>
__global__ __launch_bounds__(256) void gemm_bt(
    const u16* __restrict__ A, const u16* __restrict__ B, int K,
    const float* __restrict__ inv, const float* __restrict__ off,
    u16* __restrict__ Qb, u16* __restrict__ Kb, u16* __restrict__ Vb,
    float* __restrict__ out) {
  __shared__ __align__(16) u16 As[128 * 32];
  __shared__ __align__(16) u16 Bs[128 * 32];
  const int tid = threadIdx.x;
  const int wid = tid >> 6, lane = tid & 63;
  const int wm = wid & 1, wn = wid >> 1;
  const int fr = lane & 15, fk = (lane >> 4) << 3;
  const u16* Ab = A + (size_t)(blockIdx.y * 128) * K;
  const u16* Bb = B + (size_t)(blockIdx.x * 128) * K;
  const int c0 = (wid << 6) | lane;
  const int r0 = c0 >> 2, kc0 = (c0 & 3) << 3;
  const int c1 = c0 + 256;
  const int r1 = c1 >> 2, kc1 = (c1 & 3) << 3;

  f32x4 acc[4][4] = {};

  for (int k0 = 0; k0 < K; k0 += 32) {
    gld_lds16(Ab + (size_t)r0 * K + (k0 + kc0), &As[wid << 9]);
    gld_lds16(Ab + (size_t)r1 * K + (k0 + kc1), &As[2048 + (wid << 9)]);
    gld_lds16(Bb + (size_t)r0 * K + (k0 + kc0), &Bs[wid << 9]);
    gld_lds16(Bb + (size_t)r1 * K + (k0 + kc1), &Bs[2048 + (wid << 9)]);
    __syncthreads();
    bf16x8 av[4], bv[4];
#pragma unroll
    for (int t = 0; t < 4; t++)
      av[t] = *(const bf16x8*)&As[(wm * 64 + t * 16 + fr) * 32 + fk];
#pragma unroll
    for (int t = 0; t < 4; t++)
      bv[t] = *(const bf16x8*)&Bs[(wn * 64 + t * 16 + fr) * 32 + fk];
#pragma unroll
    for (int mt = 0; mt < 4; mt++)
#pragma unroll
      for (int nt = 0; nt < 4; nt++)
        acc[mt][nt] = __builtin_amdgcn_mfma_f32_16x16x32_bf16(av[mt], bv[nt], acc[mt][nt], 0, 0, 0);
    __syncthreads();
  }

  // C/D layout: col = lane&15, row = (lane>>4)*4 + reg   [measured m89]
  const int colb = blockIdx.x * 128 + wn * 64 + fr;
  const int rowb = blockIdx.y * 128 + wm * 64 + ((lane >> 4) << 2);
#pragma unroll
  for (int nt = 0; nt < 4; nt++) {
    const int col = colb + nt * 16;
    const float iv = inv[col], of = off[col];
    if (MODE == 0) {
      const int h = col / 192, r = col - h * 192;
#pragma unroll
      for (int mt = 0; mt < 4; mt++)
#pragma unroll
        for (int rg = 0; rg < 4; rg++) {
          const int row = rowb + mt * 16 + rg;
          const float v = acc[mt][nt][rg] * iv + of;
          const int b = row / 196, n = row - b * 196;
          const size_t bhn = (size_t)((b * NHD + h) * NQ + n);
          const u16 us = f2b(v);
          if (r < 32) Qb[bhn * 32 + r] = us;
          else if (r < 64) Kb[bhn * 32 + (r - 32)] = us;
          else Vb[bhn * 128 + (r - 64)] = us;
        }
    } else {
#pragma unroll
      for (int mt = 0; mt < 4; mt++)
#pragma unroll
        for (int rg = 0; rg < 4; rg++) {
          const int row = rowb + mt * 16 + rg;
          out[(size_t)row * DIMX + col] = acc[mt][nt][rg] * iv + of;
        }
    }
  }
}

// ---------------- attention + silu (vector fp32, bf16 LDS operands) ----------------
// one block per (b,h); 8 waves; wave handles 4 queries per job, jobs strided by 8.

__global__ __launch_bounds__(512) void attn_kernel(
    const u16* __restrict__ Qg_, const u16* __restrict__ Kg_,
    const u16* __restrict__ Vg_, const float* __restrict__ biases,
    u16* __restrict__ AO) {
  __shared__ __align__(16) u16 Qs[NQ * 32];       // [n][d]
  __shared__ __align__(16) u16 Kst[32 * NQ];      // [d][m]  (transposed: conflict-free)
  __shared__ __align__(16) u16 Vs[NQ * 128];      // [m][d]
  __shared__ __align__(16) float biasS[NQ];
  __shared__ __align__(16) float pbuf[8][4][200]; // [wave][qlocal][m]

  const int tid = threadIdx.x, wid = tid >> 6, lane = tid & 63;
  const int bh = blockIdx.x, b = bh / NHD, h = bh - b * NHD;
  const u32* Qg = (const u32*)(Qg_ + (size_t)bh * (NQ * 32));
  const u32* Kg = (const u32*)(Kg_ + (size_t)bh * (NQ * 32));
  const u32* Vg = (const u32*)(Vg_ + (size_t)bh * (NQ * 128));
  for (int i = tid; i < NQ * 16; i += 512) ((u32*)Qs)[i] = Qg[i];
  for (int i = tid; i < NQ * 16; i += 512) {
    u32 w = Kg[i];
    int n = i >> 4, d0 = (i & 15) << 1;
    Kst[d0 * NQ + n] = (u16)(w & 0xffffu);
    Kst[(d0 + 1) * NQ + n] = (u16)(w >> 16);
  }
  for (int i = tid; i < NQ * 64; i += 512) ((u32*)Vs)[i] = Vg[i];
  if (tid < NQ) biasS[tid] = biases[h * NQ + tid];
  __syncthreads();

  const int m0 = lane, m1 = lane + 64, m2 = lane + 128;
  const bool has3 = lane < 4;
  const int m3 = has3 ? lane + 192 : 0;
  const int ym0 = m0 / 14, xm0 = m0 - ym0 * 14;
  const int ym1 = m1 / 14, xm1 = m1 - ym1 * 14;
  const int ym2 = m2 / 14, xm2 = m2 - ym2 * 14;
  const int ym3 = m3 / 14, xm3 = m3 - ym3 * 14;
  const float scale = 0.17677669529663687f;  // 32^-0.5

  for (int j = wid; j < 49; j += 8) {
    const int n0 = j * 4;
    // ---- QK^T: lane covers m ∈ {lane, +64, +128, (+192)}, k-values reused over 4 queries
    float a[4][4];
#pragma unroll
    for (int q = 0; q < 4; q++) { a[q][0] = a[q][1] = a[q][2] = a[q][3] = 0.f; }
    for (int d = 0; d < 32; d++) {
      const u16* kr = &Kst[d * NQ];
      const float k0 = b2f(kr[m0]), k1 = b2f(kr[m1]), k2 = b2f(kr[m2]), k3 = b2f(kr[m3]);
#pragma unroll
      for (int q = 0; q < 4; q++) {
        const float qd = b2f(Qs[(n0 + q) * 32 + d]);
        a[q][0] += qd * k0; a[q][1] += qd * k1; a[q][2] += qd * k2; a[q][3] += qd * k3;
      }
    }
    // ---- softmax (bias via relative-position gather)
    float rinv[4];
#pragma unroll
    for (int q = 0; q < 4; q++) {
      const int n = n0 + q;
      const int yn = n / 14, xn = n - yn * 14;
      float s0 = a[q][0] * scale + biasS[iabs(yn - ym0) * 14 + iabs(xn - xm0)];
      float s1 = a[q][1] * scale + biasS[iabs(yn - ym1) * 14 + iabs(xn - xm1)];
      float s2 = a[q][2] * scale + biasS[iabs(yn - ym2) * 14 + iabs(xn - xm2)];
      float s3 = has3 ? (a[q][3] * scale + biasS[iabs(yn - ym3) * 14 + iabs(xn - xm3)]) : -1e30f;
      float mx = fmaxf(fmaxf(s0, s1), fmaxf(s2, s3));
#pragma unroll
      for (int o = 32; o; o >>= 1) mx = fmaxf(mx, __shfl_xor(mx, o));
      const float e0 = __expf(s0 - mx), e1 = __expf(s1 - mx), e2 = __expf(s2 - mx);
      const float e3 = has3 ? __expf(s3 - mx) : 0.f;
      float ls = e0 + e1 + e2 + e3;
#pragma unroll
      for (int o = 32; o; o >>= 1) ls += __shfl_xor(ls, o);
      rinv[q] = 1.f / ls;
      pbuf[wid][q][m0] = e0; pbuf[wid][q][m1] = e1; pbuf[wid][q][m2] = e2;
      if (has3) pbuf[wid][q][m3] = e3;
    }
    __threadfence_block();  // order wave-local LDS write -> cross-lane read
    // ---- PV: lane covers d = {2*lane, 2*lane+1}; p broadcast over 4 queries
    float ox[4] = {0.f, 0.f, 0.f, 0.f}, oy[4] = {0.f, 0.f, 0.f, 0.f};
    const u32* vr = (const u32*)Vs;
#pragma unroll 4
    for (int m = 0; m < NQ; m++) {
      const u32 vv = vr[(m << 6) + lane];
      const float v0 = __uint_as_float(vv << 16);
      const float v1 = __uint_as_float(vv & 0xffff0000u);
#pragma unroll
      for (int q = 0; q < 4; q++) {
        const float p = pbuf[wid][q][m];
        ox[q] += p * v0;
        oy[q] += p * v1;
      }
    }
    // ---- normalize + silu + store bf16 pair, layout (b, n, h*128+d)
#pragma unroll
    for (int q = 0; q < 4; q++) {
      float x0 = ox[q] * rinv[q], x1 = oy[q] * rinv[q];
      x0 = x0 / (1.f + __expf(-x0));
      x1 = x1 / (1.f + __expf(-x1));
      ((u32*)AO)[(size_t)(b * NQ + n0 + q) * 768 + h * 64 + lane] =
          (u32)f2b(x0) | ((u32)f2b(x1) << 16);
    }
    __threadfence_block();  // pbuf WAR before next job
  }
}

// ---------------- host launcher ----------------
// Workspace layout (lifetime-aliased):
//   [ projwb | inv1 off1 inv2 off2 | Qb Kb Vb | regionX ]
//   regionX holds { xb, qkvwb } before/during gemm0, then AO from attn onward.
//   xb+qkvwb = 21.0 MB; AO = 77.1 MB -> regionX = 77.1 MB. Total ~= 194 MB.

extern "C" void kernel_launch(void* const* d_in, const int* in_sizes, int n_in,
                              void* d_out, int out_size, void* d_ws, size_t ws_size,
                              hipStream_t stream) {
  const float* x          = (const float*)d_in[0];
  const float* qkv_w      = (const float*)d_in[1];
  const float* qkv_gamma  = (const float*)d_in[2];
  const float* qkv_beta   = (const float*)d_in[3];
  const float* qkv_mean   = (const float*)d_in[4];
  const float* qkv_var    = (const float*)d_in[5];
  const float* attn_bias  = (const float*)d_in[6];
  const float* proj_w     = (const float*)d_in[7];
  const float* proj_gamma = (const float*)d_in[8];
  const float* proj_beta  = (const float*)d_in[9];
  const float* proj_mean  = (const float*)d_in[10];
  const float* proj_var   = (const float*)d_in[11];

  const size_t szXB    = (size_t)MTOT * DIMX * 2;          // 19.3 MB
  const size_t szQKVW  = (size_t)QKVD * DIMX * 2;          //  1.8 MB
  const size_t szPROJW = (size_t)DIMX * VAD * 2;           //  1.2 MB
  const size_t szQK    = (size_t)128 * NHD * NQ * 32 * 2;  // 19.3 MB each
  const size_t szV     = (size_t)128 * NHD * NQ * 128 * 2; // 77.1 MB
  const size_t szAO    = (size_t)MTOT * VAD * 2;           // 77.1 MB
  const size_t szX     = (szXB + szQKVW > szAO) ? (szXB + szQKVW) : szAO;

  char* w = (char*)d_ws;
  u16* projwb = (u16*)w; w += szPROJW;
  float* inv1 = (float*)w; w += QKVD * 4;
  float* off1 = (float*)w; w += QKVD * 4;
  float* inv2 = (float*)w; w += DIMX * 4;
  float* off2 = (float*)w; w += DIMX * 4;
  u16* Qb = (u16*)w; w += szQK;     // (B,H,N,32)
  u16* Kb = (u16*)w; w += szQK;
  u16* Vb = (u16*)w; w += szV;      // (B,H,N,128)
  char* regionX = w; w += szX;
  u16* xb    = (u16*)regionX;               // lives: cvt -> gemm0
  u16* qkvwb = (u16*)(regionX + szXB);      // lives: cvt -> gemm0
  u16* AO    = (u16*)regionX;               // lives: attn -> gemm1 (aliases xb/qkvwb)

  if ((size_t)(w - (char*)d_ws) > ws_size) return;  // clean failure > OOB scribble

  cvt_kernel<<<MTOT * DIMX / 4 / 256, 256, 0, stream>>>(x, xb, MTOT * DIMX / 4);
  cvt_kernel<<<QKVD * DIMX / 4 / 256, 256, 0, stream>>>(qkv_w, qkvwb, QKVD * DIMX / 4);
  cvt_kernel<<<DIMX * VAD / 4 / 256, 256, 0, stream>>>(proj_w, projwb, DIMX * VAD / 4);
  bn_tab<<<(QKVD + 255) / 256, 256, 0, stream>>>(qkv_gamma, qkv_beta, qkv_mean, qkv_var, inv1, off1, QKVD);
  bn_tab<<<(DIMX + 255) / 256, 256, 0, stream>>>(proj_gamma, proj_beta, proj_mean, proj_var, inv2, off2, DIMX);

  gemm_bt<0><<<dim3(QKVD / 128, MTOT / 128), 256, 0, stream>>>(
      xb, qkvwb, DIMX, inv1, off1, Qb, Kb, Vb, nullptr);
  attn_kernel<<<128 * NHD, 512, 0, stream>>>(Qb, Kb, Vb, attn_bias, AO);
  gemm_bt<1><<<dim3(DIMX / 128, MTOT / 128), 256, 0, stream>>>(
      AO, projwb, VAD, inv2, off2, nullptr, nullptr, nullptr, (float*)d_out);
}

// Round 3
// 442.039 us; speedup vs baseline: 1.9832x; 1.9832x over previous
//
#include <hip/hip_runtime.h>
#include <cstdint>

#define NQ 196
#define DIMX 384
#define QKVD 2304
#define VAD 1536
#define NHD 12
#define MTOT 25088  // 128*196

#define KSTR 40    // u16 stride of K tile in LDS (16B-aligned rows, conflict-free b128)
#define VSTR 232   // u16 stride of V^T rows and P strips in LDS

typedef unsigned int u32;
typedef unsigned short u16;
typedef __bf16 bf16_t;
typedef bf16_t bf16x8 __attribute__((ext_vector_type(8)));
typedef float f32x4 __attribute__((ext_vector_type(4)));

__device__ inline u16 f2b(float f) {
  u32 u = __float_as_uint(f);
  u32 r = (u + 0x7fffu + ((u >> 16) & 1u)) >> 16;
  return (u16)r;
}
__device__ inline float b2f(u16 u) { return __uint_as_float(((u32)u) << 16); }
__device__ inline int iabs(int v) { return v < 0 ? -v : v; }

__device__ inline void gld_lds16(const void* g, void* l) {
  __builtin_amdgcn_global_load_lds((__attribute__((address_space(1))) void*)g,
                                   (__attribute__((address_space(3))) void*)l,
                                   16, 0, 0);
}

// ---------------- conversion / BN-table helpers ----------------

__global__ void cvt_kernel(const float* __restrict__ in, u16* __restrict__ out, int n4) {
  int i = blockIdx.x * 256 + threadIdx.x;
  if (i >= n4) return;
  float4 v = ((const float4*)in)[i];
  ushort4 o;
  o.x = f2b(v.x); o.y = f2b(v.y); o.z = f2b(v.z); o.w = f2b(v.w);
  ((ushort4*)out)[i] = o;
}

__global__ void bn_tab(const float* __restrict__ g, const float* __restrict__ be,
                       const float* __restrict__ mn, const float* __restrict__ vr,
                       float* __restrict__ inv, float* __restrict__ off, int n) {
  int i = blockIdx.x * 256 + threadIdx.x;
  if (i >= n) return;
  float iv = g[i] * rsqrtf(vr[i] + 1e-5f);
  inv[i] = iv;
  off[i] = be[i] - mn[i] * iv;
}

// ---------------- bf16 MFMA GEMM, C = A * B^T (both K-contiguous) ----------------
// MODE 0: QKV epilogue (BN fold + scatter to Q/K bf16 and V^T bf16)
// MODE 1: proj epilogue (BN fold, fp32 out)

template <int MODE>
__global__ __launch_bounds__(256) void gemm_bt(
    const u16* __restrict__ A, const u16* __restrict__ B, int K,
    const float* __restrict__ inv, const float* __restrict__ off,
    u16* __restrict__ Qb, u16* __restrict__ Kb, u16* __restrict__ Vt,
    float* __restrict__ out) {
  __shared__ __align__(16) u16 As[128 * 32];
  __shared__ __align__(16) u16 Bs[128 * 32];
  const int tid = threadIdx.x;
  const int wid = tid >> 6, lane = tid & 63;
  const int wm = wid & 1, wn = wid >> 1;
  const int fr = lane & 15, fk = (lane >> 4) << 3;
  const u16* Ab = A + (size_t)(blockIdx.y * 128) * K;
  const u16* Bb = B + (size_t)(blockIdx.x * 128) * K;
  const int c0 = (wid << 6) | lane;
  const int r0 = c0 >> 2, kc0 = (c0 & 3) << 3;
  const int c1 = c0 + 256;
  const int r1 = c1 >> 2, kc1 = (c1 & 3) << 3;

  f32x4 acc[4][4] = {};

  for (int k0 = 0; k0 < K; k0 += 32) {
    gld_lds16(Ab + (size_t)r0 * K + (k0 + kc0), &As[wid << 9]);
    gld_lds16(Ab + (size_t)r1 * K + (k0 + kc1), &As[2048 + (wid << 9)]);
    gld_lds16(Bb + (size_t)r0 * K + (k0 + kc0), &Bs[wid << 9]);
    gld_lds16(Bb + (size_t)r1 * K + (k0 + kc1), &Bs[2048 + (wid << 9)]);
    __syncthreads();
    bf16x8 av[4], bv[4];
#pragma unroll
    for (int t = 0; t < 4; t++)
      av[t] = *(const bf16x8*)&As[(wm * 64 + t * 16 + fr) * 32 + fk];
#pragma unroll
    for (int t = 0; t < 4; t++)
      bv[t] = *(const bf16x8*)&Bs[(wn * 64 + t * 16 + fr) * 32 + fk];
#pragma unroll
    for (int mt = 0; mt < 4; mt++)
#pragma unroll
      for (int nt = 0; nt < 4; nt++)
        acc[mt][nt] = __builtin_amdgcn_mfma_f32_16x16x32_bf16(av[mt], bv[nt], acc[mt][nt], 0, 0, 0);
    __syncthreads();
  }

  // C/D layout: col = lane&15, row = (lane>>4)*4 + reg   [measured m89]
  const int colb = blockIdx.x * 128 + wn * 64 + fr;
  const int rowb = blockIdx.y * 128 + wm * 64 + ((lane >> 4) << 2);
#pragma unroll
  for (int nt = 0; nt < 4; nt++) {
    const int col = colb + nt * 16;
    const float iv = inv[col], of = off[col];
    if (MODE == 0) {
      const int h = col / 192, r = col - h * 192;
#pragma unroll
      for (int mt = 0; mt < 4; mt++)
#pragma unroll
        for (int rg = 0; rg < 4; rg++) {
          const int row = rowb + mt * 16 + rg;
          const float v = acc[mt][nt][rg] * iv + of;
          const int b = row / 196, n = row - b * 196;
          const size_t bh = (size_t)(b * NHD + h);
          const u16 us = f2b(v);
          if (r < 32) Qb[(bh * NQ + n) * 32 + r] = us;
          else if (r < 64) Kb[(bh * NQ + n) * 32 + (r - 32)] = us;
          else Vt[(bh * 128 + (r - 64)) * NQ + n] = us;   // transposed (b,h,d,n)
        }
    } else {
#pragma unroll
      for (int mt = 0; mt < 4; mt++)
#pragma unroll
        for (int rg = 0; rg < 4; rg++) {
          const int row = rowb + mt * 16 + rg;
          out[(size_t)row * DIMX + col] = acc[mt][nt][rg] * iv + of;
        }
    }
  }
}

// ---------------- MFMA tile attention + silu ----------------
// one block per (b,h); 8 waves; wave owns row-tiles rt = wid, wid+8.
// S = Q K^T (13x13 tiles of 16x16, one mfma each), softmax in C-layout regs,
// P -> per-wave LDS strip (bf16), O = P V via mfma over 7 k-chunks of 32.

__global__ __launch_bounds__(512) void attn_kernel(
    const u16* __restrict__ Qg, const u16* __restrict__ Kg,
    const u16* __restrict__ Vtg, const float* __restrict__ biases,
    u16* __restrict__ AO) {
  __shared__ __align__(16) u16 Ks[208 * KSTR];       // [m][k], stride 40
  __shared__ __align__(16) u16 Vs[128 * VSTR];       // [d][m], stride 232, m-pad zeroed
  __shared__ __align__(16) u16 Ps[8][16 * VSTR];     // per-wave P strip [row][m]
  __shared__ __align__(16) float biasS[NQ];

  const int tid = threadIdx.x, wid = tid >> 6, lane = tid & 63;
  const int fr = lane & 15, fj = lane >> 4, fk = fj << 3;
  const int bh = blockIdx.x, b = bh / NHD, h = bh - b * NHD;
  const float scale = 0.17677669529663687f;  // 32^-0.5

  // ---- stage K (196x32) -> Ks stride 40
  for (int i = tid; i < NQ * 4; i += 512) {
    const int m = i >> 2, kc = (i & 3) << 3;
    uint4 v = *(const uint4*)(Kg + ((size_t)bh * NQ + m) * 32 + kc);
    *(uint4*)&Ks[m * KSTR + kc] = v;
  }
  // ---- stage V^T (128x196) -> Vs stride 232, then zero cols [196,232)
  {
    const u32* src = (const u32*)(Vtg + (size_t)bh * 128 * NQ);
    u32* dst = (u32*)Vs;
    for (int i = tid; i < 128 * 98; i += 512) {
      const int d = i / 98, nc = i - d * 98;
      dst[d * (VSTR / 2) + nc] = src[i];
    }
    for (int i = tid; i < 128 * 18; i += 512) {
      const int d = i / 18, nc = 98 + (i - d * 18);
      dst[d * (VSTR / 2) + nc] = 0u;
    }
  }
  if (tid < NQ) biasS[tid] = biases[h * NQ + tid];
  // ---- zero P strip pad cols [208,224) (wave-local)
  {
    const int row = lane >> 2, c = 208 + (lane & 3) * 4;
    *(uint2*)&Ps[wid][row * VSTR + c] = make_uint2(0u, 0u);
  }
  __syncthreads();

  for (int rt = wid; rt < 13; rt += 8) {
    // ---- Q fragment (A-operand): row = fr, k = fk..fk+7, direct from global
    int qrow = rt * 16 + fr; qrow = qrow > 195 ? 195 : qrow;
    const bf16x8 qf = *(const bf16x8*)(Qg + ((size_t)bh * NQ + qrow) * 32 + fk);

    // ---- S strip: 13 tiles, one mfma each (K=32 complete)
    f32x4 s[13];
#pragma unroll
    for (int t = 0; t < 13; t++) {
      const bf16x8 kf = *(const bf16x8*)&Ks[(t * 16 + fr) * KSTR + fk];
      f32x4 z = {0.f, 0.f, 0.f, 0.f};
      s[t] = __builtin_amdgcn_mfma_f32_16x16x32_bf16(qf, kf, z, 0, 0, 0);
    }

    // ---- rows this lane holds (C layout): n = rt*16 + fj*4 + reg
    int yn[4], xn[4];
#pragma unroll
    for (int rg = 0; rg < 4; rg++) {
      int n = rt * 16 + fj * 4 + rg;
      int y = (n * 586) >> 13; y = y > 13 ? 13 : y;
      yn[rg] = y; xn[rg] = n - y * 14;
    }
    // ---- bias + scale + mask (col m = t*16 + fr)
#pragma unroll
    for (int t = 0; t < 13; t++) {
      const int m = t * 16 + fr;
      const bool valid = m < NQ;
      int ym = (m * 586) >> 13; ym = ym > 13 ? 13 : ym;
      const int xm = m - ym * 14;
#pragma unroll
      for (int rg = 0; rg < 4; rg++) {
        int idx = iabs(yn[rg] - ym) * 14 + iabs(xn[rg] - xm);
        idx = idx > 195 ? 195 : idx;
        const float bv = biasS[idx];
        s[t][rg] = valid ? (s[t][rg] * scale + bv) : -1e30f;
      }
    }
    // ---- softmax per row (reduce across fr lanes: xor 1,2,4,8)
    float rinv[4];
#pragma unroll
    for (int rg = 0; rg < 4; rg++) {
      float mx = s[0][rg];
#pragma unroll
      for (int t = 1; t < 13; t++) mx = fmaxf(mx, s[t][rg]);
      mx = fmaxf(mx, __shfl_xor(mx, 1));
      mx = fmaxf(mx, __shfl_xor(mx, 2));
      mx = fmaxf(mx, __shfl_xor(mx, 4));
      mx = fmaxf(mx, __shfl_xor(mx, 8));
      float ls = 0.f;
#pragma unroll
      for (int t = 0; t < 13; t++) {
        const float e = __expf(s[t][rg] - mx);
        s[t][rg] = e;
        ls += e;
      }
      ls += __shfl_xor(ls, 1);
      ls += __shfl_xor(ls, 2);
      ls += __shfl_xor(ls, 4);
      ls += __shfl_xor(ls, 8);
      rinv[rg] = 1.f / ls;
    }
    // ---- write P strip (bf16, unnormalized): row = fj*4+rg, col = t*16+fr
#pragma unroll
    for (int t = 0; t < 13; t++)
#pragma unroll
      for (int rg = 0; rg < 4; rg++)
        Ps[wid][(fj * 4 + rg) * VSTR + t * 16 + fr] = f2b(s[t][rg]);
    __threadfence_block();  // drain LDS writes before wave-local re-read

    // ---- O = P V : 8 d-tiles x 7 k-chunks
    f32x4 o[8] = {};
#pragma unroll
    for (int kc = 0; kc < 7; kc++) {
      const bf16x8 pf = *(const bf16x8*)&Ps[wid][fr * VSTR + kc * 32 + fk];
#pragma unroll
      for (int dt = 0; dt < 8; dt++) {
        const bf16x8 vf = *(const bf16x8*)&Vs[(dt * 16 + fr) * VSTR + kc * 32 + fk];
        o[dt] = __builtin_amdgcn_mfma_f32_16x16x32_bf16(pf, vf, o[dt], 0, 0, 0);
      }
    }
    // ---- normalize + silu + store (C layout: col d = dt*16+fr, row n)
#pragma unroll
    for (int rg = 0; rg < 4; rg++) {
      const int n = rt * 16 + fj * 4 + rg;
      if (n < NQ) {
        const float rv = rinv[rg];
#pragma unroll
        for (int dt = 0; dt < 8; dt++) {
          float x = o[dt][rg] * rv;
          x = x / (1.f + __expf(-x));
          AO[((size_t)(b * NQ + n)) * VAD + h * 128 + dt * 16 + fr] = f2b(x);
        }
      }
    }
    __threadfence_block();  // WAR: P strip reused next row-tile
  }
}

// ---------------- host launcher ----------------
// Workspace layout (lifetime-aliased), ~194 MB total (same as passing r2 run):
//   [ projwb | inv1 off1 inv2 off2 | Qb Kb Vt | regionX ]
//   regionX holds { xb, qkvwb } through gemm0, then AO from attn onward.

extern "C" void kernel_launch(void* const* d_in, const int* in_sizes, int n_in,
                              void* d_out, int out_size, void* d_ws, size_t ws_size,
                              hipStream_t stream) {
  const float* x          = (const float*)d_in[0];
  const float* qkv_w      = (const float*)d_in[1];
  const float* qkv_gamma  = (const float*)d_in[2];
  const float* qkv_beta   = (const float*)d_in[3];
  const float* qkv_mean   = (const float*)d_in[4];
  const float* qkv_var    = (const float*)d_in[5];
  const float* attn_bias  = (const float*)d_in[6];
  const float* proj_w     = (const float*)d_in[7];
  const float* proj_gamma = (const float*)d_in[8];
  const float* proj_beta  = (const float*)d_in[9];
  const float* proj_mean  = (const float*)d_in[10];
  const float* proj_var   = (const float*)d_in[11];

  const size_t szXB    = (size_t)MTOT * DIMX * 2;
  const size_t szQKVW  = (size_t)QKVD * DIMX * 2;
  const size_t szPROJW = (size_t)DIMX * VAD * 2;
  const size_t szQK    = (size_t)128 * NHD * NQ * 32 * 2;
  const size_t szV     = (size_t)128 * NHD * 128 * NQ * 2;
  const size_t szAO    = (size_t)MTOT * VAD * 2;
  const size_t szX     = (szXB + szQKVW > szAO) ? (szXB + szQKVW) : szAO;

  char* w = (char*)d_ws;
  u16* projwb = (u16*)w; w += szPROJW;
  float* inv1 = (float*)w; w += QKVD * 4;
  float* off1 = (float*)w; w += QKVD * 4;
  float* inv2 = (float*)w; w += DIMX * 4;
  float* off2 = (float*)w; w += DIMX * 4;
  u16* Qb = (u16*)w; w += szQK;     // (B,H,N,32)
  u16* Kb = (u16*)w; w += szQK;     // (B,H,N,32)
  u16* Vt = (u16*)w; w += szV;      // (B,H,128,N) transposed
  char* regionX = w; w += szX;
  u16* xb    = (u16*)regionX;
  u16* qkvwb = (u16*)(regionX + szXB);
  u16* AO    = (u16*)regionX;       // aliases xb/qkvwb (disjoint lifetimes)

  if ((size_t)(w - (char*)d_ws) > ws_size) return;  // clean failure > OOB scribble

  cvt_kernel<<<MTOT * DIMX / 4 / 256, 256, 0, stream>>>(x, xb, MTOT * DIMX / 4);
  cvt_kernel<<<QKVD * DIMX / 4 / 256, 256, 0, stream>>>(qkv_w, qkvwb, QKVD * DIMX / 4);
  cvt_kernel<<<DIMX * VAD / 4 / 256, 256, 0, stream>>>(proj_w, projwb, DIMX * VAD / 4);
  bn_tab<<<(QKVD + 255) / 256, 256, 0, stream>>>(qkv_gamma, qkv_beta, qkv_mean, qkv_var, inv1, off1, QKVD);
  bn_tab<<<(DIMX + 255) / 256, 256, 0, stream>>>(proj_gamma, proj_beta, proj_mean, proj_var, inv2, off2, DIMX);

  gemm_bt<0><<<dim3(QKVD / 128, MTOT / 128), 256, 0, stream>>>(
      xb, qkvwb, DIMX, inv1, off1, Qb, Kb, Vt, nullptr);
  attn_kernel<<<128 * NHD, 512, 0, stream>>>(Qb, Kb, Vt, attn_bias, AO);
  gemm_bt<1><<<dim3(DIMX / 128, MTOT / 128), 256, 0, stream>>>(
      AO, projwb, VAD, inv2, off2, nullptr, nullptr, nullptr, (float*)d_out);
}

// Round 4
// 401.580 us; speedup vs baseline: 2.1830x; 1.1007x over previous
//
#include <hip/hip_runtime.h>
#include <cstdint>

#define NQ 196
#define DIMX 384
#define QKVD 2304
#define VAD 1536
#define NHD 12
#define MTOT 25088  // 128*196

#define KSTR 40    // u16 stride of K tile in attn LDS
#define VSTR 232   // u16 stride of V^T rows and P strips in attn LDS
#define TSTR 140   // u16 stride of gemm0 epilogue LDS tile (280B rows: 8B-aligned, bank-clean)

typedef unsigned int u32;
typedef unsigned short u16;
typedef __bf16 bf16_t;
typedef bf16_t bf16x8 __attribute__((ext_vector_type(8)));
typedef float f32x4 __attribute__((ext_vector_type(4)));

__device__ inline u16 f2b(float f) {
  u32 u = __float_as_uint(f);
  u32 r = (u + 0x7fffu + ((u >> 16) & 1u)) >> 16;
  return (u16)r;
}
__device__ inline float b2f(u16 u) { return __uint_as_float(((u32)u) << 16); }
__device__ inline int iabs(int v) { return v < 0 ? -v : v; }

__device__ inline void gld_lds16(const void* g, void* l) {
  __builtin_amdgcn_global_load_lds((__attribute__((address_space(1))) void*)g,
                                   (__attribute__((address_space(3))) void*)l,
                                   16, 0, 0);
}

// ---------------- conversion / BN-table helpers ----------------

__global__ void cvt_kernel(const float* __restrict__ in, u16* __restrict__ out, int n4) {
  int i = blockIdx.x * 256 + threadIdx.x;
  if (i >= n4) return;
  float4 v = ((const float4*)in)[i];
  ushort4 o;
  o.x = f2b(v.x); o.y = f2b(v.y); o.z = f2b(v.z); o.w = f2b(v.w);
  ((ushort4*)out)[i] = o;
}

// QKV weight: bf16 + row reorder so new cols = [Q 12*32 | K 12*32 | V 12*128]
__global__ void cvt_wqkv(const float* __restrict__ in, u16* __restrict__ out) {
  int i = blockIdx.x * 256 + threadIdx.x;
  if (i >= QKVD * DIMX / 4) return;
  const int newc = i / (DIMX / 4);
  const int kc = (i - newc * (DIMX / 4)) * 4;
  int oldc;
  if (newc < 384)      { int h = newc >> 5;              oldc = h * 192 + (newc & 31); }
  else if (newc < 768) { int t = newc - 384; int h = t >> 5; oldc = h * 192 + 32 + (t & 31); }
  else                 { int t = newc - 768; int h = t >> 7; oldc = h * 192 + 64 + (t & 127); }
  float4 v = *(const float4*)(in + (size_t)oldc * DIMX + kc);
  ushort4 o;
  o.x = f2b(v.x); o.y = f2b(v.y); o.z = f2b(v.z); o.w = f2b(v.w);
  *(ushort4*)(out + (size_t)newc * DIMX + kc) = o;
}

__global__ void bn_tab(const float* __restrict__ g, const float* __restrict__ be,
                       const float* __restrict__ mn, const float* __restrict__ vr,
                       float* __restrict__ inv, float* __restrict__ off, int n) {
  int i = blockIdx.x * 256 + threadIdx.x;
  if (i >= n) return;
  float iv = g[i] * rsqrtf(vr[i] + 1e-5f);
  inv[i] = iv;
  off[i] = be[i] - mn[i] * iv;
}

// BN table for QKV, written in the reordered column order
__global__ void bn_tab_qkv(const float* __restrict__ g, const float* __restrict__ be,
                           const float* __restrict__ mn, const float* __restrict__ vr,
                           float* __restrict__ inv, float* __restrict__ off) {
  int i = blockIdx.x * 256 + threadIdx.x;  // old column index
  if (i >= QKVD) return;
  const int h = i / 192, r = i - h * 192;
  const int newc = (r < 32) ? h * 32 + r
                 : (r < 64) ? 384 + h * 32 + (r - 32)
                            : 768 + h * 128 + (r - 64);
  float iv = g[i] * rsqrtf(vr[i] + 1e-5f);
  inv[newc] = iv;
  off[newc] = be[i] - mn[i] * iv;
}

// ---------------- bf16 MFMA GEMM, C = A * B^T (both K-contiguous) ----------------
// MODE 0: QKV (reordered cols). Epilogue: BN fold -> LDS tile -> vector stores.
//   blocks 0-2: Q (4 heads each), 3-5: K, 6-17: V (1 head each, stored transposed (b,h,d,n)).
// MODE 1: proj epilogue (BN fold, fp32 out)

template <int MODE>
__global__ __launch_bounds__(256) void gemm_bt(
    const u16* __restrict__ A, const u16* __restrict__ B, int K,
    const float* __restrict__ inv, const float* __restrict__ off,
    u16* __restrict__ Qb, u16* __restrict__ Kb, u16* __restrict__ Vt,
    float* __restrict__ out) {
  constexpr int LDSU = (MODE == 0) ? 128 * TSTR : 8192;  // epilogue tile unions As/Bs
  __shared__ __align__(16) u16 lds[LDSU];
  u16* As = lds;
  u16* Bs = lds + 4096;
  const int tid = threadIdx.x;
  const int wid = tid >> 6, lane = tid & 63;
  const int wm = wid & 1, wn = wid >> 1;
  const int fr = lane & 15, fk = (lane >> 4) << 3;
  const u16* Ab = A + (size_t)(blockIdx.y * 128) * K;
  const u16* Bb = B + (size_t)(blockIdx.x * 128) * K;
  const int c0 = (wid << 6) | lane;
  const int r0 = c0 >> 2, kc0 = (c0 & 3) << 3;
  const int c1 = c0 + 256;
  const int r1 = c1 >> 2, kc1 = (c1 & 3) << 3;

  f32x4 acc[4][4] = {};

  for (int k0 = 0; k0 < K; k0 += 32) {
    gld_lds16(Ab + (size_t)r0 * K + (k0 + kc0), &As[wid << 9]);
    gld_lds16(Ab + (size_t)r1 * K + (k0 + kc1), &As[2048 + (wid << 9)]);
    gld_lds16(Bb + (size_t)r0 * K + (k0 + kc0), &Bs[wid << 9]);
    gld_lds16(Bb + (size_t)r1 * K + (k0 + kc1), &Bs[2048 + (wid << 9)]);
    __syncthreads();
    bf16x8 av[4], bv[4];
#pragma unroll
    for (int t = 0; t < 4; t++)
      av[t] = *(const bf16x8*)&As[(wm * 64 + t * 16 + fr) * 32 + fk];
#pragma unroll
    for (int t = 0; t < 4; t++)
      bv[t] = *(const bf16x8*)&Bs[(wn * 64 + t * 16 + fr) * 32 + fk];
#pragma unroll
    for (int mt = 0; mt < 4; mt++)
#pragma unroll
      for (int nt = 0; nt < 4; nt++)
        acc[mt][nt] = __builtin_amdgcn_mfma_f32_16x16x32_bf16(av[mt], bv[nt], acc[mt][nt], 0, 0, 0);
    __syncthreads();
  }

  // C/D layout: col = lane&15 (+16*nt +64*wn), row = (lane>>4)*4 + reg (+16*mt +64*wm)
  const int lrow0 = wm * 64 + ((lane >> 4) << 2);
  const int lcol0 = wn * 64 + fr;

  if (MODE == 0) {
    const int bx = blockIdx.x, by = blockIdx.y;
    const bool isV = bx >= 6;
    // ---- write phase: BN fold + f2b -> LDS tile (row-major Q/K, col-major V)
#pragma unroll
    for (int nt = 0; nt < 4; nt++) {
      const int lc = lcol0 + nt * 16;
      const int gc = bx * 128 + lc;
      const float iv = inv[gc], of = off[gc];
#pragma unroll
      for (int mt = 0; mt < 4; mt++)
#pragma unroll
        for (int rg = 0; rg < 4; rg++) {
          const int lr = lrow0 + mt * 16 + rg;
          const u16 us = f2b(acc[mt][nt][rg] * iv + of);
          if (isV) lds[lc * TSTR + lr] = us;
          else     lds[lr * TSTR + lc] = us;
        }
    }
    __syncthreads();
    // ---- store phase: vector stores, block-uniform mapping
    if (!isV) {
      u16* dstB = (bx < 3) ? Qb : Kb;
      const int h0 = (bx < 3 ? bx : bx - 3) * 4;
#pragma unroll
      for (int it = 0; it < 8; it++) {
        const int idx = it * 256 + tid;
        const int ch = idx & 3, hl = (idx >> 2) & 3, row = idx >> 4;
        const int rowg = by * 128 + row;
        const int b = rowg / 196, n = rowg - b * 196;
        const size_t bh = (size_t)(b * NHD + h0 + hl);
        const u16* src = &lds[row * TSTR + hl * 32 + ch * 8];
        uint2 a0 = *(const uint2*)src;
        uint2 a1 = *(const uint2*)(src + 4);
        *(uint4*)(dstB + (bh * NQ + n) * 32 + ch * 8) = make_uint4(a0.x, a0.y, a1.x, a1.y);
      }
    } else {
      const int h = bx - 6;
#pragma unroll
      for (int it = 0; it < 16; it++) {
        const int idx = it * 256 + tid;
        const int nk = idx & 31, col = idx >> 5;
        const int rowg = by * 128 + nk * 4;       // 4 rows, never cross b (196 % 4 == 0)
        const int b = rowg / 196, n = rowg - b * 196;
        uint2 v = *(const uint2*)&lds[col * TSTR + nk * 4];
        *(uint2*)(Vt + ((size_t)(b * NHD + h) * 128 + col) * NQ + n) = v;
      }
    }
  } else {
    const int colb = blockIdx.x * 128 + lcol0;
    const int rowb = blockIdx.y * 128 + lrow0;
#pragma unroll
    for (int nt = 0; nt < 4; nt++) {
      const int col = colb + nt * 16;
      const float iv = inv[col], of = off[col];
#pragma unroll
      for (int mt = 0; mt < 4; mt++)
#pragma unroll
        for (int rg = 0; rg < 4; rg++) {
          const int row = rowb + mt * 16 + rg;
          out[(size_t)row * DIMX + col] = acc[mt][nt][rg] * iv + of;
        }
    }
  }
}

// ---------------- MFMA tile attention + silu (unchanged from r3) ----------------

__global__ __launch_bounds__(512) void attn_kernel(
    const u16* __restrict__ Qg, const u16* __restrict__ Kg,
    const u16* __restrict__ Vtg, const float* __restrict__ biases,
    u16* __restrict__ AO) {
  __shared__ __align__(16) u16 Ks[208 * KSTR];
  __shared__ __align__(16) u16 Vs[128 * VSTR];
  __shared__ __align__(16) u16 Ps[8][16 * VSTR];
  __shared__ __align__(16) float biasS[NQ];

  const int tid = threadIdx.x, wid = tid >> 6, lane = tid & 63;
  const int fr = lane & 15, fj = lane >> 4, fk = fj << 3;
  const int bh = blockIdx.x, b = bh / NHD, h = bh - b * NHD;
  const float scale = 0.17677669529663687f;

  for (int i = tid; i < NQ * 4; i += 512) {
    const int m = i >> 2, kc = (i & 3) << 3;
    uint4 v = *(const uint4*)(Kg + ((size_t)bh * NQ + m) * 32 + kc);
    *(uint4*)&Ks[m * KSTR + kc] = v;
  }
  {
    const u32* src = (const u32*)(Vtg + (size_t)bh * 128 * NQ);
    u32* dst = (u32*)Vs;
    for (int i = tid; i < 128 * 98; i += 512) {
      const int d = i / 98, nc = i - d * 98;
      dst[d * (VSTR / 2) + nc] = src[i];
    }
    for (int i = tid; i < 128 * 18; i += 512) {
      const int d = i / 18, nc = 98 + (i - d * 18);
      dst[d * (VSTR / 2) + nc] = 0u;
    }
  }
  if (tid < NQ) biasS[tid] = biases[h * NQ + tid];
  {
    const int row = lane >> 2, c = 208 + (lane & 3) * 4;
    *(uint2*)&Ps[wid][row * VSTR + c] = make_uint2(0u, 0u);
  }
  __syncthreads();

  for (int rt = wid; rt < 13; rt += 8) {
    int qrow = rt * 16 + fr; qrow = qrow > 195 ? 195 : qrow;
    const bf16x8 qf = *(const bf16x8*)(Qg + ((size_t)bh * NQ + qrow) * 32 + fk);

    f32x4 s[13];
#pragma unroll
    for (int t = 0; t < 13; t++) {
      const bf16x8 kf = *(const bf16x8*)&Ks[(t * 16 + fr) * KSTR + fk];
      f32x4 z = {0.f, 0.f, 0.f, 0.f};
      s[t] = __builtin_amdgcn_mfma_f32_16x16x32_bf16(qf, kf, z, 0, 0, 0);
    }

    int yn[4], xn[4];
#pragma unroll
    for (int rg = 0; rg < 4; rg++) {
      int n = rt * 16 + fj * 4 + rg;
      int y = (n * 586) >> 13; y = y > 13 ? 13 : y;
      yn[rg] = y; xn[rg] = n - y * 14;
    }
#pragma unroll
    for (int t = 0; t < 13; t++) {
      const int m = t * 16 + fr;
      const bool valid = m < NQ;
      int ym = (m * 586) >> 13; ym = ym > 13 ? 13 : ym;
      const int xm = m - ym * 14;
#pragma unroll
      for (int rg = 0; rg < 4; rg++) {
        int idx = iabs(yn[rg] - ym) * 14 + iabs(xn[rg] - xm);
        idx = idx > 195 ? 195 : idx;
        const float bv = biasS[idx];
        s[t][rg] = valid ? (s[t][rg] * scale + bv) : -1e30f;
      }
    }
    float rinv[4];
#pragma unroll
    for (int rg = 0; rg < 4; rg++) {
      float mx = s[0][rg];
#pragma unroll
      for (int t = 1; t < 13; t++) mx = fmaxf(mx, s[t][rg]);
      mx = fmaxf(mx, __shfl_xor(mx, 1));
      mx = fmaxf(mx, __shfl_xor(mx, 2));
      mx = fmaxf(mx, __shfl_xor(mx, 4));
      mx = fmaxf(mx, __shfl_xor(mx, 8));
      float ls = 0.f;
#pragma unroll
      for (int t = 0; t < 13; t++) {
        const float e = __expf(s[t][rg] - mx);
        s[t][rg] = e;
        ls += e;
      }
      ls += __shfl_xor(ls, 1);
      ls += __shfl_xor(ls, 2);
      ls += __shfl_xor(ls, 4);
      ls += __shfl_xor(ls, 8);
      rinv[rg] = 1.f / ls;
    }
#pragma unroll
    for (int t = 0; t < 13; t++)
#pragma unroll
      for (int rg = 0; rg < 4; rg++)
        Ps[wid][(fj * 4 + rg) * VSTR + t * 16 + fr] = f2b(s[t][rg]);
    __threadfence_block();

    f32x4 o[8] = {};
#pragma unroll
    for (int kc = 0; kc < 7; kc++) {
      const bf16x8 pf = *(const bf16x8*)&Ps[wid][fr * VSTR + kc * 32 + fk];
#pragma unroll
      for (int dt = 0; dt < 8; dt++) {
        const bf16x8 vf = *(const bf16x8*)&Vs[(dt * 16 + fr) * VSTR + kc * 32 + fk];
        o[dt] = __builtin_amdgcn_mfma_f32_16x16x32_bf16(pf, vf, o[dt], 0, 0, 0);
      }
    }
#pragma unroll
    for (int rg = 0; rg < 4; rg++) {
      const int n = rt * 16 + fj * 4 + rg;
      if (n < NQ) {
        const float rv = rinv[rg];
#pragma unroll
        for (int dt = 0; dt < 8; dt++) {
          float x = o[dt][rg] * rv;
          x = x / (1.f + __expf(-x));
          AO[((size_t)(b * NQ + n)) * VAD + h * 128 + dt * 16 + fr] = f2b(x);
        }
      }
    }
    __threadfence_block();
  }
}

// ---------------- host launcher ----------------

extern "C" void kernel_launch(void* const* d_in, const int* in_sizes, int n_in,
                              void* d_out, int out_size, void* d_ws, size_t ws_size,
                              hipStream_t stream) {
  const float* x          = (const float*)d_in[0];
  const float* qkv_w      = (const float*)d_in[1];
  const float* qkv_gamma  = (const float*)d_in[2];
  const float* qkv_beta   = (const float*)d_in[3];
  const float* qkv_mean   = (const float*)d_in[4];
  const float* qkv_var    = (const float*)d_in[5];
  const float* attn_bias  = (const float*)d_in[6];
  const float* proj_w     = (const float*)d_in[7];
  const float* proj_gamma = (const float*)d_in[8];
  const float* proj_beta  = (const float*)d_in[9];
  const float* proj_mean  = (const float*)d_in[10];
  const float* proj_var   = (const float*)d_in[11];

  const size_t szXB    = (size_t)MTOT * DIMX * 2;
  const size_t szQKVW  = (size_t)QKVD * DIMX * 2;
  const size_t szPROJW = (size_t)DIMX * VAD * 2;
  const size_t szQK    = (size_t)128 * NHD * NQ * 32 * 2;
  const size_t szV     = (size_t)128 * NHD * 128 * NQ * 2;
  const size_t szAO    = (size_t)MTOT * VAD * 2;
  const size_t szX     = (szXB + szQKVW > szAO) ? (szXB + szQKVW) : szAO;

  char* w = (char*)d_ws;
  u16* projwb = (u16*)w; w += szPROJW;
  float* inv1 = (float*)w; w += QKVD * 4;
  float* off1 = (float*)w; w += QKVD * 4;
  float* inv2 = (float*)w; w += DIMX * 4;
  float* off2 = (float*)w; w += DIMX * 4;
  u16* Qb = (u16*)w; w += szQK;     // (B,H,N,32)
  u16* Kb = (u16*)w; w += szQK;     // (B,H,N,32)
  u16* Vt = (u16*)w; w += szV;      // (B,H,128,N) transposed
  char* regionX = w; w += szX;
  u16* xb    = (u16*)regionX;
  u16* qkvwb = (u16*)(regionX + szXB);
  u16* AO    = (u16*)regionX;       // aliases xb/qkvwb (disjoint lifetimes)

  if ((size_t)(w - (char*)d_ws) > ws_size) return;

  cvt_kernel<<<MTOT * DIMX / 4 / 256, 256, 0, stream>>>(x, xb, MTOT * DIMX / 4);
  cvt_wqkv<<<(QKVD * DIMX / 4 + 255) / 256, 256, 0, stream>>>(qkv_w, qkvwb);
  cvt_kernel<<<DIMX * VAD / 4 / 256, 256, 0, stream>>>(proj_w, projwb, DIMX * VAD / 4);
  bn_tab_qkv<<<(QKVD + 255) / 256, 256, 0, stream>>>(qkv_gamma, qkv_beta, qkv_mean, qkv_var, inv1, off1);
  bn_tab<<<(DIMX + 255) / 256, 256, 0, stream>>>(proj_gamma, proj_beta, proj_mean, proj_var, inv2, off2, DIMX);

  gemm_bt<0><<<dim3(QKVD / 128, MTOT / 128), 256, 0, stream>>>(
      xb, qkvwb, DIMX, inv1, off1, Qb, Kb, Vt, nullptr);
  attn_kernel<<<128 * NHD, 512, 0, stream>>>(Qb, Kb, Vt, attn_bias, AO);
  gemm_bt<1><<<dim3(DIMX / 128, MTOT / 128), 256, 0, stream>>>(
      AO, projwb, VAD, inv2, off2, nullptr, nullptr, nullptr, (float*)d_out);
}